// Round 9
// baseline (1005.312 us; speedup 1.0000x reference)
//
#include <hip/hip_runtime.h>
#include <hip/hip_bf16.h>

// MoE block: H=2048, F=8192, E=8, top-2, T=512 tokens. All inputs fp32.
// Round 9: attack the 2.1 TB/s HBM plateau = 256B-segment page thrash.
// BN=256 tiles -> every weight-row read is a full-wave 1KB contiguous
// global_load_lds. gemm1 split into two passes (W1 -> h1 fp32; W3 ->
// h=relu(h1)*h3 bf16) so LDS = 3 x 32KB per kernel. A direct-to-reg and
// the r8-proven 3-buffer depth-2 rotation with counted vmcnt(12/8/0).

#define HDIM 2048
#define FDIM 8192
#define NEXP 8
#define NTOK 512
#define MAXT 512

typedef __attribute__((ext_vector_type(8))) short short8;
typedef __attribute__((ext_vector_type(4))) float f32x4;
typedef unsigned int u32;
typedef unsigned short u16;

__device__ __forceinline__ unsigned cvtpk(float lo, float hi) {
    unsigned r;
    asm("v_cvt_pk_bf16_f32 %0, %1, %2" : "=v"(r) : "v"(lo), "v"(hi));
    return r;
}
__device__ __forceinline__ unsigned f2bf1(float f) {
    unsigned u = __builtin_bit_cast(unsigned, f);
    return (u + 0x7FFFu + ((u >> 16) & 1u)) >> 16;
}
__device__ __forceinline__ void gload16(const void* g, void* l) {
    __builtin_amdgcn_global_load_lds((const __attribute__((address_space(1))) u32*)g,
                                     (__attribute__((address_space(3))) u32*)l, 16, 0, 0);
}
#define SBAR() __builtin_amdgcn_sched_barrier(0)

// ---------------------------------------------------------------- router
__global__ void moe_router(const float* __restrict__ x, const float* __restrict__ Wg,
                           int* __restrict__ counts, int* __restrict__ tok_id,
                           float* __restrict__ tok_w) {
    const int t = blockIdx.x;
    const int lane = threadIdx.x;
    const float* xr = x + (size_t)t * HDIM;
    float acc[8];
    #pragma unroll
    for (int e = 0; e < 8; ++e) acc[e] = 0.f;
    #pragma unroll 4
    for (int i = 0; i < HDIM / 64; ++i) {
        int h = lane + i * 64;
        float xv = xr[h];
        const float4* wr = (const float4*)(Wg + (size_t)h * 8);
        float4 wa = wr[0], wb = wr[1];
        acc[0] += xv * wa.x; acc[1] += xv * wa.y; acc[2] += xv * wa.z; acc[3] += xv * wa.w;
        acc[4] += xv * wb.x; acc[5] += xv * wb.y; acc[6] += xv * wb.z; acc[7] += xv * wb.w;
    }
    #pragma unroll
    for (int off = 32; off >= 1; off >>= 1) {
        #pragma unroll
        for (int e = 0; e < 8; ++e) acc[e] += __shfl_xor(acc[e], off);
    }
    if (lane == 0) {
        int e0 = 0;
        #pragma unroll
        for (int e = 1; e < 8; ++e) if (acc[e] > acc[e0]) e0 = e;
        int e1 = (e0 == 0) ? 1 : 0;
        #pragma unroll
        for (int e = 0; e < 8; ++e) if (e != e0 && acc[e] > acc[e1]) e1 = e;
        float w0 = 1.f / (1.f + __expf(acc[e1] - acc[e0]));
        float w1 = 1.f - w0;
        int s0 = atomicAdd(&counts[e0], 1);
        tok_id[e0 * MAXT + s0] = t; tok_w[e0 * MAXT + s0] = w0;
        int s1 = atomicAdd(&counts[e1], 1);
        tok_id[e1 * MAXT + s1] = t; tok_w[e1 * MAXT + s1] = w1;
    }
}

__global__ void moe_scan(const int* __restrict__ counts, int* __restrict__ offsets) {
    if (threadIdx.x == 0) {
        int a = 0;
        for (int e = 0; e < NEXP; ++e) { offsets[e] = a; a += counts[e]; }
    }
}

// ------------------------------------------------------------- x -> bf16
__global__ void moe_xcvt(const float* __restrict__ x, u16* __restrict__ xbf) {
    const int i = (blockIdx.x * 256 + threadIdx.x) * 8;
    float4 a = *(const float4*)(x + i);
    float4 b = *(const float4*)(x + i + 4);
    uint4 q;
    q.x = cvtpk(a.x, a.y); q.y = cvtpk(a.z, a.w);
    q.z = cvtpk(b.x, b.y); q.w = cvtpk(b.z, b.w);
    *(uint4*)(xbf + i) = q;
}

// B-fragment: weights fp32 in LDS as [32 k][256 n], dword col n' =
// n ^ (((k>>3)&1)<<4). 8x ds_read_b32 (2-way = free) + 4 cvt_pk.
__device__ __forceinline__ short8 bfrag256(const float* sB, int kbase, int nsw) {
    const float* p = sB + kbase * 256 + nsw;
    float f[8];
    #pragma unroll
    for (int j = 0; j < 8; ++j) f[j] = p[j * 256];
    uint4 q;
    q.x = cvtpk(f[0], f[1]); q.y = cvtpk(f[2], f[3]);
    q.z = cvtpk(f[4], f[5]); q.w = cvtpk(f[6], f[7]);
    return __builtin_bit_cast(short8, q);
}

// ---------------------------------------------------------------- GEMM1 pass
// pass 0: h1 = x W1 (fp32 -> h1buf). pass 1: h = relu(h1) * (x W3) -> hbuf.
// BM=128 BN=256 BK=32, 512 thr (8 waves, 2M x 4N). B rows staged as full-wave
// 1KB contiguous gload16. A direct global->VGPR fragments (xbf L2-resident).
__global__ __launch_bounds__(512, 1)
void moe_gemm1(const u16* __restrict__ xbf, const float* __restrict__ W,
               const int* __restrict__ counts, const int* __restrict__ offsets,
               const int* __restrict__ tok_id, float* __restrict__ h1buf,
               u16* __restrict__ hbuf, int pass) {
    const int g = blockIdx.x;                       // 0..31
    const int nt = (g & 7) * 4 + (g >> 3);          // XCD-chunked: adjacent 1KB segs share XCD
    const int mt = blockIdx.y, e = blockIdx.z;
    const int cnt = counts[e];
    if (mt * 128 >= cnt) return;
    const int n0 = nt * 256;
    const int tid = threadIdx.x;
    const int w = tid >> 6, l = tid & 63;

    __shared__ __align__(16) float sB[3][32 * 256];   // 96 KB

    const int wr = (w >> 2) * 64, wc = (w & 3) * 64;
    const int lr = l & 15, lg = l >> 4;
    const int lk = lg * 8;
    const int g1 = lg & 1;

    // A fragment bases: lane covers row wr+mi*16+lr, k-chunk lg*8.
    const u16* abase[4];
    #pragma unroll
    for (int mi = 0; mi < 4; ++mi) {
        int slot = mt * 128 + wr + mi * 16 + lr;
        int tok = tok_id[e * MAXT + (slot < cnt ? slot : cnt - 1)];
        abase[mi] = xbf + (size_t)tok * HDIM + lk;
    }
    // B row sources: instr j covers k-row r = w + 8j (full-wave 1KB row);
    // source dword col = (l ^ ((j&1)<<2))*4  (octet pre-XOR, o = (r>>3)&1 = j&1).
    const size_t wstride = (size_t)HDIM * FDIM;
    const float* bsrc[4];
    #pragma unroll
    for (int j = 0; j < 4; ++j)
        bsrc[j] = W + (size_t)e * wstride + (size_t)(w + 8 * j) * FDIM + n0 +
                  ((l ^ ((j & 1) << 2)) * 4);

    f32x4 acc[4][4];
    #pragma unroll
    for (int mi = 0; mi < 4; ++mi)
        #pragma unroll
        for (int ni = 0; ni < 4; ++ni) acc[mi][ni] = (f32x4)0.f;

    uint4 afA[4], afB[4];
    unsigned o0 = 0, o1 = 1, o2 = 2;

    #define AISSUE(AF, kt)                                                     \
        _Pragma("unroll")                                                      \
        for (int mi = 0; mi < 4; ++mi)                                         \
            AF[mi] = *(const uint4*)(abase[mi] + (size_t)(kt) * 32);
    #define BSTAGE(ob, kt)                                                     \
        _Pragma("unroll")                                                      \
        for (int j = 0; j < 4; ++j)                                            \
            gload16(bsrc[j] + (size_t)(kt) * 32 * FDIM, &sB[ob][(w + 8 * j) * 256]);
    #define MFMAP(AF, ob)                                                      \
        _Pragma("unroll")                                                      \
        for (int ni = 0; ni < 4; ++ni) {                                       \
            const int nsw = (wc + ni * 16 + lr) ^ (g1 << 4);                   \
            short8 b = bfrag256(sB[ob], lk, nsw);                              \
            _Pragma("unroll")                                                  \
            for (int mi = 0; mi < 4; ++mi) {                                   \
                short8 a_ = __builtin_bit_cast(short8, AF[mi]);                \
                acc[mi][ni] = __builtin_amdgcn_mfma_f32_16x16x32_bf16(a_, b, acc[mi][ni], 0, 0, 0); \
            }                                                                  \
        }
    #define BODY(kt, oCur, oStg, ARD, ALD, VM)                                 \
        SBAR(); AISSUE(ALD, (kt) + 1); SBAR();                                 \
        BSTAGE(oStg, (kt) + 2); SBAR();                                        \
        asm volatile("s_waitcnt vmcnt(" VM ")" ::: "memory"); SBAR();          \
        __builtin_amdgcn_s_barrier(); SBAR();                                  \
        MFMAP(ARD, oCur); SBAR();                                              \
        __builtin_amdgcn_s_barrier();

    // Prologue: queue = [B0(4), A0(4), B1(4)] = 12.
    BSTAGE(o0, 0); SBAR();
    AISSUE(afA, 0); SBAR();
    BSTAGE(o1, 1);
    for (int kt = 0; kt < 62; kt += 2) {
        BODY(kt, o0, o2, afA, afB, "12");
        BODY(kt + 1, o1, o0, afB, afA, "12");
        unsigned t_ = o0; o0 = o2; o2 = o1; o1 = t_;
    }
    // Tail kt=62: queue [B62,A62,B63,A63]=16 -> vmcnt(8).
    SBAR(); AISSUE(afB, 63); SBAR();
    asm volatile("s_waitcnt vmcnt(8)" ::: "memory"); SBAR();
    __builtin_amdgcn_s_barrier(); SBAR();
    MFMAP(afA, o0); SBAR();
    __builtin_amdgcn_s_barrier(); SBAR();
    asm volatile("s_waitcnt vmcnt(0)" ::: "memory"); SBAR();
    __builtin_amdgcn_s_barrier(); SBAR();
    MFMAP(afB, o1); SBAR();

    #undef AISSUE
    #undef BSTAGE
    #undef MFMAP
    #undef BODY

    // ---- epilogue
    const int hbase = offsets[e] + mt * 128;
    #pragma unroll
    for (int mi = 0; mi < 4; ++mi)
        #pragma unroll
        for (int ni = 0; ni < 4; ++ni)
            #pragma unroll
            for (int r = 0; r < 4; ++r) {
                int rl = wr + mi * 16 + (l >> 4) * 4 + r;
                int sl = mt * 128 + rl;
                if (sl < cnt) {
                    size_t idx = (size_t)(hbase + rl) * FDIM + (n0 + wc + ni * 16 + lr);
                    if (pass == 0) {
                        h1buf[idx] = acc[mi][ni][r];
                    } else {
                        float v1 = h1buf[idx];
                        v1 = v1 > 0.f ? v1 : 0.f;
                        hbuf[idx] = (u16)f2bf1(v1 * acc[mi][ni][r]);
                    }
                }
            }
}

// ---------------------------------------------------------------- GEMM2
// out[t,n] += w * (h W2). BM=128 BN=256 BK=32, split-K x4 (2048 each).
// Same 8-wave structure; W2 rows contiguous along H (1KB wave reads).
__global__ __launch_bounds__(512, 1)
void moe_gemm2(const u16* __restrict__ hbuf, const float* __restrict__ W2,
               const int* __restrict__ counts, const int* __restrict__ offsets,
               const int* __restrict__ tok_id, const float* __restrict__ tok_w,
               float* __restrict__ out) {
    const int nt = blockIdx.x, e = blockIdx.z;      // nt 0..7
    const int mt = blockIdx.y & 3, ksp = blockIdx.y >> 2;
    const int cnt = counts[e];
    if (mt * 128 >= cnt) return;
    const int n0 = nt * 256;
    const int tid = threadIdx.x;
    const int w = tid >> 6, l = tid & 63;

    __shared__ __align__(16) float sB[3][32 * 256];   // 96 KB

    const int wr = (w >> 2) * 64, wc = (w & 3) * 64;
    const int lr = l & 15, lg = l >> 4;
    const int lk = lg * 8;
    const int g1 = lg & 1;

    const u16* abase[4];
    #pragma unroll
    for (int mi = 0; mi < 4; ++mi) {
        int hrow = offsets[e] + mt * 128 + wr + mi * 16 + lr;  // tail rows stale, masked below
        abase[mi] = hbuf + (size_t)hrow * FDIM + ksp * 2048 + lk;
    }
    const float* bsrc[4];
    #pragma unroll
    for (int j = 0; j < 4; ++j)
        bsrc[j] = W2 + (size_t)e * ((size_t)FDIM * HDIM) +
                  (size_t)(ksp * 2048 + w + 8 * j) * HDIM + n0 +
                  ((l ^ ((j & 1) << 2)) * 4);

    f32x4 acc[4][4];
    #pragma unroll
    for (int mi = 0; mi < 4; ++mi)
        #pragma unroll
        for (int ni = 0; ni < 4; ++ni) acc[mi][ni] = (f32x4)0.f;

    uint4 afA[4], afB[4];
    unsigned o0 = 0, o1 = 1, o2 = 2;

    #define AISSUE(AF, kt)                                                     \
        _Pragma("unroll")                                                      \
        for (int mi = 0; mi < 4; ++mi)                                         \
            AF[mi] = *(const uint4*)(abase[mi] + (size_t)(kt) * 32);
    #define BSTAGE(ob, kt)                                                     \
        _Pragma("unroll")                                                      \
        for (int j = 0; j < 4; ++j)                                            \
            gload16(bsrc[j] + (size_t)(kt) * 32 * HDIM, &sB[ob][(w + 8 * j) * 256]);
    #define MFMAP(AF, ob)                                                      \
        _Pragma("unroll")                                                      \
        for (int ni = 0; ni < 4; ++ni) {                                       \
            const int nsw = (wc + ni * 16 + lr) ^ (g1 << 4);                   \
            short8 b = bfrag256(sB[ob], lk, nsw);                              \
            _Pragma("unroll")                                                  \
            for (int mi = 0; mi < 4; ++mi) {                                   \
                short8 a_ = __builtin_bit_cast(short8, AF[mi]);                \
                acc[mi][ni] = __builtin_amdgcn_mfma_f32_16x16x32_bf16(a_, b, acc[mi][ni], 0, 0, 0); \
            }                                                                  \
        }
    #define BODY(kt, oCur, oStg, ARD, ALD, VM)                                 \
        SBAR(); AISSUE(ALD, (kt) + 1); SBAR();                                 \
        BSTAGE(oStg, (kt) + 2); SBAR();                                        \
        asm volatile("s_waitcnt vmcnt(" VM ")" ::: "memory"); SBAR();          \
        __builtin_amdgcn_s_barrier(); SBAR();                                  \
        MFMAP(ARD, oCur); SBAR();                                              \
        __builtin_amdgcn_s_barrier();

    BSTAGE(o0, 0); SBAR();
    AISSUE(afA, 0); SBAR();
    BSTAGE(o1, 1);
    for (int kt = 0; kt < 62; kt += 2) {
        BODY(kt, o0, o2, afA, afB, "12");
        BODY(kt + 1, o1, o0, afB, afA, "12");
        unsigned t_ = o0; o0 = o2; o2 = o1; o1 = t_;
    }
    SBAR(); AISSUE(afB, 63); SBAR();
    asm volatile("s_waitcnt vmcnt(8)" ::: "memory"); SBAR();
    __builtin_amdgcn_s_barrier(); SBAR();
    MFMAP(afA, o0); SBAR();
    __builtin_amdgcn_s_barrier(); SBAR();
    asm volatile("s_waitcnt vmcnt(0)" ::: "memory"); SBAR();
    __builtin_amdgcn_s_barrier(); SBAR();
    MFMAP(afB, o1); SBAR();

    #undef AISSUE
    #undef BSTAGE
    #undef MFMAP
    #undef BODY

    // ---- epilogue: scaled partial scatter-add
    #pragma unroll
    for (int mi = 0; mi < 4; ++mi)
        #pragma unroll
        for (int ni = 0; ni < 4; ++ni)
            #pragma unroll
            for (int r = 0; r < 4; ++r) {
                int rl = wr + mi * 16 + (l >> 4) * 4 + r;
                int sl = mt * 128 + rl;
                if (sl < cnt) {
                    int tk = tok_id[e * MAXT + sl];
                    float wgt = tok_w[e * MAXT + sl];
                    atomicAdd(&out[(size_t)tk * HDIM + (n0 + wc + ni * 16 + lr)],
                              wgt * acc[mi][ni][r]);
                }
            }
}

// ---------------------------------------------------------------- launch
extern "C" void kernel_launch(void* const* d_in, const int* in_sizes, int n_in,
                              void* d_out, int out_size, void* d_ws, size_t ws_size,
                              hipStream_t stream) {
    const float* x  = (const float*)d_in[0];
    const float* Wg = (const float*)d_in[1];
    const float* W1 = (const float*)d_in[2];
    const float* W2 = (const float*)d_in[3];
    const float* W3 = (const float*)d_in[4];
    float* out = (float*)d_out;

    char* ws = (char*)d_ws;
    int*   counts  = (int*)(ws + 0);
    int*   offsets = (int*)(ws + 32);
    int*   tok_id  = (int*)(ws + 64);
    float* tok_w   = (float*)(ws + 64 + NEXP * MAXT * 4);
    u16*   xbf     = (u16*)(ws + 65536);                      // 512x2048 bf16 = 2MB
    float* h1buf   = (float*)(ws + 65536 + 2097152);          // 1152x8192 fp32 = 37.75MB
    u16*   hbuf    = (u16*)(ws + 65536 + 2097152 + 37748736); // 1152x8192 bf16 = 18.9MB

    hipMemsetAsync(ws, 0, 64, stream);
    hipMemsetAsync(d_out, 0, (size_t)out_size * sizeof(float), stream);

    moe_router<<<NTOK, 64, 0, stream>>>(x, Wg, counts, tok_id, tok_w);
    moe_scan<<<1, 64, 0, stream>>>(counts, offsets);
    moe_xcvt<<<NTOK * HDIM / (256 * 8), 256, 0, stream>>>(x, xbf);
    moe_gemm1<<<dim3(32, 4, NEXP), 512, 0, stream>>>(xbf, W1, counts, offsets, tok_id, h1buf, hbuf, 0);
    moe_gemm1<<<dim3(32, 4, NEXP), 512, 0, stream>>>(xbf, W3, counts, offsets, tok_id, h1buf, hbuf, 1);
    moe_gemm2<<<dim3(8, 16, NEXP), 512, 0, stream>>>(hbuf, W2, counts, offsets, tok_id, tok_w, out);
}